// Round 20
// baseline (19.336 us; speedup 1.0000x reference)
//
#include <hip/hip_runtime.h>

// CapsNet dynamic routing, fused, MFMA, 8 waves/block, 1 element/block.
// u = x@W never materialized (linear in x):
//   PA: y[j][k] = c(A) @ x(B)          PB: blogT[j][i] += wt(A) @ xT(B)
// x fragments are round-invariant bf16 register caches (xA[4], xB[2][2]);
// blog persists in 4 MFMA C-fragments/wave.
// R20 = R17 (18.7us best) + 3 BLOCKS/CU (the untested occupancy point;
// R13/R14 trend: 2 blocks/CU=20.3 < 1 block/CU=21.1 -> independent barrier
// chains fill each other's stalls). To fit 3: Wl LDS stage dropped (W from
// global, 20KB L1/L2-resident; R11 valued Wl+desync together at only ~1us)
// -> LDS ~41KB; __launch_bounds__(512,3) caps VGPR at ~84 (R9's identical
// cache set compiled to 80). Spill tripwire: WRITE_SIZE.

#define NJ 10
#define NT 512
#define CW_STRIDE 72    // shorts/row of cw slab: 144 B
#define WT_STRIDE 40    // shorts/row of wtb: 80 B
#define Y_STRIDE 36     // f32/row: 144 B

typedef __attribute__((ext_vector_type(8))) short short8;
typedef __attribute__((ext_vector_type(4))) float f32x4;

__device__ __forceinline__ unsigned cvt_pk_bf16(float lo, float hi) {
    unsigned d;
    asm volatile("v_cvt_pk_bf16_f32 %0, %1, %2" : "=v"(d) : "v"(lo), "v"(hi));
    return d;
}
__device__ __forceinline__ short f2bf(float f) {   // RNE f32->bf16
    unsigned u = __float_as_uint(f);
    return (short)((u + 0x7FFFu + ((u >> 16) & 1u)) >> 16);
}

// add value rotated by N within the 16-lane DPP row (VALU pipe, not DS)
#define ROR_ADD(v, CTRL)                                                      \
    { int _t = __builtin_amdgcn_update_dpp(0, __float_as_int(v), CTRL, 0xF,   \
                                           0xF, false);                       \
      v += __int_as_float(_t); }
// ring allreduce within 16-lane row: every lane ends with the row sum
#define ROW_SUM16(v) { ROR_ADD(v, 0x128); ROR_ADD(v, 0x124);                  \
                       ROR_ADD(v, 0x122); ROR_ADD(v, 0x121); }

__global__ __launch_bounds__(NT, 3) void capsnet_kernel(
    const float* __restrict__ x, const float* __restrict__ W,
    float* __restrict__ out)
{
    __shared__ __attribute__((aligned(16))) short cw[8][16][CW_STRIDE];   // 18,432 B (first 1KB = csum overlay)
    __shared__ __attribute__((aligned(16))) float ypart[8][16][Y_STRIDE]; // 18,432 B
    __shared__ __attribute__((aligned(16))) short wtb[16 * WT_STRIDE];    //  1,280 B
    __shared__ __attribute__((aligned(16))) float yb[16 * Y_STRIDE];      //  2,304 B
    __shared__ __attribute__((aligned(16))) float ob[160];
    __shared__ float lgt[16];
    // total ~41.2 KB -> 3 blocks/CU

    const int tid  = threadIdx.x;
    const int b    = blockIdx.x;
    const int lane = tid & 63;
    const int w    = tid >> 6;            // wave 0..7
    const int l15  = lane & 15;
    const int lg4  = lane >> 4;           // quad 0..3
    const float* xg = x + (size_t)b * (512 * 32);

    // desync co-resident generations so barrier stalls interleave
    if (b & 256) __builtin_amdgcn_s_sleep(10);

    // ---- staging: xA/xB frags + f32 colsum partials (x read once) ----
    float cs[8];
    #pragma unroll
    for (int q = 0; q < 8; ++q) cs[q] = 0.f;
    short8 xA[4];        // PB B-frag: x[w*64+T*16+l15][lg4*8..+7]
    #pragma unroll
    for (int T = 0; T < 4; ++T) {
        const float* p = xg + ((w << 6) + (T << 4) + l15) * 32 + (lg4 << 3);
        const float4 a0 = *reinterpret_cast<const float4*>(p);
        const float4 a1 = *reinterpret_cast<const float4*>(p + 4);
        cs[0] += a0.x; cs[1] += a0.y; cs[2] += a0.z; cs[3] += a0.w;
        cs[4] += a1.x; cs[5] += a1.y; cs[6] += a1.z; cs[7] += a1.w;
        union { unsigned u[4]; short8 s8; } cv;
        cv.u[0] = cvt_pk_bf16(a0.x, a0.y);
        cv.u[1] = cvt_pk_bf16(a0.z, a0.w);
        cv.u[2] = cvt_pk_bf16(a1.x, a1.y);
        cv.u[3] = cvt_pk_bf16(a1.z, a1.w);
        xA[T] = cv.s8;
    }
    short8 xB[2][2];     // PA B-frag: B[i=(2w+ss)*32+lg4*8+q][k=l15+16t]
    #pragma unroll
    for (int ss = 0; ss < 2; ++ss) {
        const int ib = ((w << 1) + ss) << 5;
        #pragma unroll
        for (int t = 0; t < 2; ++t) {
            const float* p = xg + (ib + (lg4 << 3)) * 32 + l15 + (t << 4);
            union { unsigned u[4]; short8 s8; } cv;
            cv.u[0] = cvt_pk_bf16(p[0 * 32], p[1 * 32]);
            cv.u[1] = cvt_pk_bf16(p[2 * 32], p[3 * 32]);
            cv.u[2] = cvt_pk_bf16(p[4 * 32], p[5 * 32]);
            cv.u[3] = cvt_pk_bf16(p[6 * 32], p[7 * 32]);
            xB[ss][t] = cv.s8;
        }
    }
    // colsum reduce over l15 via DPP ring (VALU pipe; lg4 rows independent)
    #pragma unroll
    for (int q = 0; q < 8; ++q) { ROW_SUM16(cs[q]); }
    float* csum = reinterpret_cast<float*>(&cw[0][0][0]);   // [8][32] overlay
    if (l15 == 0) {
        #pragma unroll
        for (int q = 0; q < 8; ++q) csum[(w << 5) + (lg4 << 3) + q] = cs[q];
    }
    if (tid < 240) wtb[400 + tid] = 0;        // zero wtb rows 10..15 (once)
    __syncthreads();

    // ---- y0 = 0.1 * colsum (c uniform = 1/J), f32-exact ----
    if (tid < 32) {
        float s = 0.f;
        #pragma unroll
        for (int ww = 0; ww < 8; ++ww) s += csum[(ww << 5) + tid];
        s *= 0.1f;
        #pragma unroll
        for (int j = 0; j < NJ; ++j) yb[j * Y_STRIDE + tid] = s;
    }
    __syncthreads();

    f32x4 blogA[4];      // blogT[j=lg4*4+rr][i=w*64+T*16+l15], persists all rounds
    #pragma unroll
    for (int T = 0; T < 4; ++T) blogA[T] = (f32x4){0.f, 0.f, 0.f, 0.f};

    for (int r = 0; r < 3; ++r) {
        // ===== S+WT fused (160 threads): squash -> o; wt rows k=d,d+16 =====
        if (tid < 160) {
            const int j = tid >> 4, d = tid & 15;
            float sa = 0.f, sb = 0.f;         // even/odd k4 partials (2x ILP)
            #pragma unroll
            for (int k4 = 0; k4 < 8; k4 += 2) {
                const float4 y4a = *reinterpret_cast<const float4*>(&yb[j * Y_STRIDE + (k4 << 2)]);
                const float4 y4b = *reinterpret_cast<const float4*>(&yb[j * Y_STRIDE + ((k4 + 1) << 2)]);
                const float* wpa = W + (k4 << 2) * 160 + (j << 4) + d;
                const float* wpb = wpa + 4 * 160;
                sa = fmaf(y4a.x, wpa[0],       sa);
                sb = fmaf(y4b.x, wpb[0],       sb);
                sa = fmaf(y4a.y, wpa[160],     sa);
                sb = fmaf(y4b.y, wpb[160],     sb);
                sa = fmaf(y4a.z, wpa[320],     sa);
                sb = fmaf(y4b.z, wpb[320],     sb);
                sa = fmaf(y4a.w, wpa[480],     sa);
                sb = fmaf(y4b.w, wpb[480],     sb);
            }
            const float s = sa + sb;
            float sq = s * s;
            ROW_SUM16(sq);                    // sum over d (16-lane row), VALU
            const float scale = (sq / (1.f + sq)) / sqrtf(sq + 1e-7f);
            const float o_ = s * scale;
            if (r == 2) {
                float ss = o_;
                ROW_SUM16(ss);                // logits[j] = sum_d o[j][d]
                if (d == 0) lgt[j] = ss;
            } else {
                ob[tid] = o_;
                // same-wave LDS dep: all 16 lanes of group j wrote above
                const float4* o4p = reinterpret_cast<const float4*>(&ob[j << 4]);
                const float4 o0 = o4p[0], o1 = o4p[1], o2 = o4p[2], o3 = o4p[3];
                #pragma unroll
                for (int t = 0; t < 2; ++t) {
                    const int k = d + (t << 4);
                    const float4* wr = reinterpret_cast<const float4*>(W + k * 160 + (j << 4));
                    const float4 w0 = wr[0], w1 = wr[1], w2 = wr[2], w3 = wr[3];
                    float wa = w0.x * o0.x + w0.y * o0.y + w0.z * o0.z + w0.w * o0.w;
                    float wb = w1.x * o1.x + w1.y * o1.y + w1.z * o1.z + w1.w * o1.w;
                    wa += w2.x * o2.x + w2.y * o2.y + w2.z * o2.z + w2.w * o2.w;
                    wb += w3.x * o3.x + w3.y * o3.y + w3.z * o3.z + w3.w * o3.w;
                    wtb[j * WT_STRIDE + k] = f2bf(wa + wb);
                }
            }
        }
        __syncthreads();
        if (r == 2) break;

        // ===== PB + PA fused (wave-private cw: no internal barrier) =====
        {
            __builtin_amdgcn_s_setprio(1);
            const short8 wf = *reinterpret_cast<const short8*>(&wtb[l15 * WT_STRIDE + (lg4 << 3)]);
            #pragma unroll
            for (int T = 0; T < 4; ++T)
                blogA[T] = __builtin_amdgcn_mfma_f32_16x16x32_bf16(wf, xA[T], blogA[T], 0, 0, 0);
            const int jb = lg4 << 2;
            #pragma unroll
            for (int T = 0; T < 4; ++T) {
                const f32x4 bv = blogA[T];
                const float e0 = (jb + 0 < NJ) ? __expf(bv[0]) : 0.f;
                const float e1 = (jb + 1 < NJ) ? __expf(bv[1]) : 0.f;
                const float e2 = (jb + 2 < NJ) ? __expf(bv[2]) : 0.f;
                const float e3 = (jb + 3 < NJ) ? __expf(bv[3]) : 0.f;
                float ssum = e0 + e1 + e2 + e3;
                ssum += __shfl_xor(ssum, 16);
                ssum += __shfl_xor(ssum, 32);
                const float inv = 1.f / ssum;
                const int il = (T << 4) + l15;          // wave-local column
                cw[w][jb + 0][il] = f2bf(e0 * inv);
                cw[w][jb + 1][il] = f2bf(e1 * inv);
                cw[w][jb + 2][il] = f2bf(e2 * inv);
                cw[w][jb + 3][il] = f2bf(e3 * inv);
            }
            // PA over wave's own 64 i's (2 K-steps), same-wave LDS
            f32x4 yf0 = (f32x4){0.f, 0.f, 0.f, 0.f};
            f32x4 yf1 = (f32x4){0.f, 0.f, 0.f, 0.f};
            #pragma unroll
            for (int ss = 0; ss < 2; ++ss) {
                const short8 ca = *reinterpret_cast<const short8*>(
                    &cw[w][l15][(ss << 5) + (lg4 << 3)]);
                yf0 = __builtin_amdgcn_mfma_f32_16x16x32_bf16(ca, xB[ss][0], yf0, 0, 0, 0);
                yf1 = __builtin_amdgcn_mfma_f32_16x16x32_bf16(ca, xB[ss][1], yf1, 0, 0, 0);
            }
            __builtin_amdgcn_s_setprio(0);
            #pragma unroll
            for (int rr = 0; rr < 4; ++rr) {
                ypart[w][(lg4 << 2) + rr][l15]      = yf0[rr];
                ypart[w][(lg4 << 2) + rr][l15 + 16] = yf1[rr];
            }
        }
        __syncthreads();

        // ===== reduce 8-wave partials -> yb =====
        {
            const int j = tid >> 5, k = tid & 31;
            float s = 0.f;
            #pragma unroll
            for (int ww = 0; ww < 8; ++ww) s += ypart[ww][j][k];
            yb[j * Y_STRIDE + k] = s;
        }
        __syncthreads();
    }

    // ---- final softmax over j, write out[b][0..9] ----
    if (tid < NJ) {
        float m = -1e30f;
        #pragma unroll
        for (int j = 0; j < NJ; ++j) m = fmaxf(m, lgt[j]);
        float sum = 0.f;
        #pragma unroll
        for (int j = 0; j < NJ; ++j) sum += __expf(lgt[j] - m);
        out[b * NJ + tid] = __expf(lgt[tid] - m) / sum;
    }
}

extern "C" void kernel_launch(void* const* d_in, const int* in_sizes, int n_in,
                              void* d_out, int out_size, void* d_ws, size_t ws_size,
                              hipStream_t stream) {
    (void)in_sizes; (void)n_in; (void)d_ws; (void)ws_size; (void)out_size;
    const float* x = (const float*)d_in[0];
    const float* W = (const float*)d_in[1];
    float* out = (float*)d_out;
    hipLaunchKernelGGL(capsnet_kernel, dim3(512), dim3(NT), 0, stream, x, W, out);
}

// Round 21
// 18.653 us; speedup vs baseline: 1.0367x; 1.0367x over previous
//
#include <hip/hip_runtime.h>

// CapsNet dynamic routing, fused, MFMA, 8 waves/block, 1 element/block.
// u = x@W never materialized (linear in x):
//   PA: y[j][k] = c(A) @ x(B)          PB: blogT[j][i] += wt(A) @ xT(B)
// x fragments are round-invariant bf16 register caches (xA[4], xB[2][2]);
// blog persists in 4 MFMA C-fragments/wave.
// R21 = R17 verbatim (session best: 18.67us, absmax 0.0039) — consolidation
// after R18-R20 perturbations all landed null or worse. Key levers that got
// here: algebraic collapse (u never materialized), MFMA for broadcast inner
// products, register-cached round-invariant x fragments, wave-private c-slab
// phase fusion, and DS-pipe -> VALU (DPP row_ror) reductions.

#define NJ 10
#define NT 512
#define CW_STRIDE 72    // shorts/row of cw slab: 144 B
#define WT_STRIDE 40    // shorts/row of wtb: 80 B
#define Y_STRIDE 36     // f32/row: 144 B
#define WL_STRIDE 164   // f32/row of Wl: 656 B (pad: bank stride 4)

typedef __attribute__((ext_vector_type(8))) short short8;
typedef __attribute__((ext_vector_type(4))) float f32x4;

__device__ __forceinline__ unsigned cvt_pk_bf16(float lo, float hi) {
    unsigned d;
    asm volatile("v_cvt_pk_bf16_f32 %0, %1, %2" : "=v"(d) : "v"(lo), "v"(hi));
    return d;
}
__device__ __forceinline__ short f2bf(float f) {   // RNE f32->bf16
    unsigned u = __float_as_uint(f);
    return (short)((u + 0x7FFFu + ((u >> 16) & 1u)) >> 16);
}

// add value rotated by N within the 16-lane DPP row (VALU pipe, not DS)
#define ROR_ADD(v, CTRL)                                                      \
    { int _t = __builtin_amdgcn_update_dpp(0, __float_as_int(v), CTRL, 0xF,   \
                                           0xF, false);                       \
      v += __int_as_float(_t); }
// ring allreduce within 16-lane row: every lane ends with the row sum
#define ROW_SUM16(v) { ROR_ADD(v, 0x128); ROR_ADD(v, 0x124);                  \
                       ROR_ADD(v, 0x122); ROR_ADD(v, 0x121); }

__global__ __launch_bounds__(NT, 2) void capsnet_kernel(
    const float* __restrict__ x, const float* __restrict__ W,
    float* __restrict__ out)
{
    __shared__ __attribute__((aligned(16))) short cw[8][16][CW_STRIDE];   // 18,432 B (first 1KB = csum overlay)
    __shared__ __attribute__((aligned(16))) float ypart[8][16][Y_STRIDE]; // 18,432 B
    __shared__ __attribute__((aligned(16))) float Wl[32 * WL_STRIDE];     // 20,992 B
    __shared__ __attribute__((aligned(16))) short wtb[16 * WT_STRIDE];    //  1,280 B
    __shared__ __attribute__((aligned(16))) float yb[16 * Y_STRIDE];      //  2,304 B
    __shared__ __attribute__((aligned(16))) float ob[160];
    __shared__ float lgt[16];

    const int tid  = threadIdx.x;
    const int b    = blockIdx.x;
    const int lane = tid & 63;
    const int w    = tid >> 6;            // wave 0..7
    const int l15  = lane & 15;
    const int lg4  = lane >> 4;           // quad 0..3
    const float* xg = x + (size_t)b * (512 * 32);

    // desync co-resident generations so barrier stalls interleave
    if (b & 256) __builtin_amdgcn_s_sleep(10);

    // ---- staging: W -> LDS (padded), xA/xB frags + f32 colsum partials ----
    {
        const float4* W4 = reinterpret_cast<const float4*>(W);
        #pragma unroll
        for (int e = tid; e < 1280; e += NT) {
            const float4 v = W4[e];
            const int flat = e << 2;
            const int row  = flat / 160;
            const int col  = flat - row * 160;     // %4 == 0 -> 16B-aligned
            *reinterpret_cast<float4*>(&Wl[row * WL_STRIDE + col]) = v;
        }
    }
    float cs[8];
    #pragma unroll
    for (int q = 0; q < 8; ++q) cs[q] = 0.f;
    short8 xA[4];        // PB B-frag: x[w*64+T*16+l15][lg4*8..+7]
    #pragma unroll
    for (int T = 0; T < 4; ++T) {
        const float* p = xg + ((w << 6) + (T << 4) + l15) * 32 + (lg4 << 3);
        const float4 a0 = *reinterpret_cast<const float4*>(p);
        const float4 a1 = *reinterpret_cast<const float4*>(p + 4);
        cs[0] += a0.x; cs[1] += a0.y; cs[2] += a0.z; cs[3] += a0.w;
        cs[4] += a1.x; cs[5] += a1.y; cs[6] += a1.z; cs[7] += a1.w;
        union { unsigned u[4]; short8 s8; } cv;
        cv.u[0] = cvt_pk_bf16(a0.x, a0.y);
        cv.u[1] = cvt_pk_bf16(a0.z, a0.w);
        cv.u[2] = cvt_pk_bf16(a1.x, a1.y);
        cv.u[3] = cvt_pk_bf16(a1.z, a1.w);
        xA[T] = cv.s8;
    }
    short8 xB[2][2];     // PA B-frag: B[i=(2w+ss)*32+lg4*8+q][k=l15+16t]
    #pragma unroll
    for (int ss = 0; ss < 2; ++ss) {
        const int ib = ((w << 1) + ss) << 5;
        #pragma unroll
        for (int t = 0; t < 2; ++t) {
            const float* p = xg + (ib + (lg4 << 3)) * 32 + l15 + (t << 4);
            union { unsigned u[4]; short8 s8; } cv;
            cv.u[0] = cvt_pk_bf16(p[0 * 32], p[1 * 32]);
            cv.u[1] = cvt_pk_bf16(p[2 * 32], p[3 * 32]);
            cv.u[2] = cvt_pk_bf16(p[4 * 32], p[5 * 32]);
            cv.u[3] = cvt_pk_bf16(p[6 * 32], p[7 * 32]);
            xB[ss][t] = cv.s8;
        }
    }
    // colsum reduce over l15 via DPP ring (VALU pipe; lg4 rows independent)
    #pragma unroll
    for (int q = 0; q < 8; ++q) { ROW_SUM16(cs[q]); }
    float* csum = reinterpret_cast<float*>(&cw[0][0][0]);   // [8][32] overlay
    if (l15 == 0) {
        #pragma unroll
        for (int q = 0; q < 8; ++q) csum[(w << 5) + (lg4 << 3) + q] = cs[q];
    }
    if (tid < 240) wtb[400 + tid] = 0;        // zero wtb rows 10..15 (once)
    __syncthreads();

    // ---- y0 = 0.1 * colsum (c uniform = 1/J), f32-exact ----
    if (tid < 32) {
        float s = 0.f;
        #pragma unroll
        for (int ww = 0; ww < 8; ++ww) s += csum[(ww << 5) + tid];
        s *= 0.1f;
        #pragma unroll
        for (int j = 0; j < NJ; ++j) yb[j * Y_STRIDE + tid] = s;
    }
    __syncthreads();

    f32x4 blogA[4];      // blogT[j=lg4*4+rr][i=w*64+T*16+l15], persists all rounds
    #pragma unroll
    for (int T = 0; T < 4; ++T) blogA[T] = (f32x4){0.f, 0.f, 0.f, 0.f};

    for (int r = 0; r < 3; ++r) {
        // ===== S+WT fused (160 threads): squash -> o; wt rows k=d,d+16 =====
        if (tid < 160) {
            const int j = tid >> 4, d = tid & 15;
            float sa = 0.f, sb = 0.f;         // even/odd k4 partials (2x ILP)
            #pragma unroll
            for (int k4 = 0; k4 < 8; k4 += 2) {
                const float4 y4a = *reinterpret_cast<const float4*>(&yb[j * Y_STRIDE + (k4 << 2)]);
                const float4 y4b = *reinterpret_cast<const float4*>(&yb[j * Y_STRIDE + ((k4 + 1) << 2)]);
                const float* wpa = &Wl[(k4 << 2) * WL_STRIDE + (j << 4) + d];
                const float* wpb = wpa + 4 * WL_STRIDE;
                sa = fmaf(y4a.x, wpa[0],             sa);
                sb = fmaf(y4b.x, wpb[0],             sb);
                sa = fmaf(y4a.y, wpa[WL_STRIDE],     sa);
                sb = fmaf(y4b.y, wpb[WL_STRIDE],     sb);
                sa = fmaf(y4a.z, wpa[2 * WL_STRIDE], sa);
                sb = fmaf(y4b.z, wpb[2 * WL_STRIDE], sb);
                sa = fmaf(y4a.w, wpa[3 * WL_STRIDE], sa);
                sb = fmaf(y4b.w, wpb[3 * WL_STRIDE], sb);
            }
            const float s = sa + sb;
            float sq = s * s;
            ROW_SUM16(sq);                    // sum over d (16-lane row), VALU
            const float scale = (sq / (1.f + sq)) / sqrtf(sq + 1e-7f);
            const float o_ = s * scale;
            if (r == 2) {
                float ss = o_;
                ROW_SUM16(ss);                // logits[j] = sum_d o[j][d]
                if (d == 0) lgt[j] = ss;
            } else {
                ob[tid] = o_;
                // same-wave LDS dep: all 16 lanes of group j wrote above
                const float4* o4p = reinterpret_cast<const float4*>(&ob[j << 4]);
                const float4 o0 = o4p[0], o1 = o4p[1], o2 = o4p[2], o3 = o4p[3];
                #pragma unroll
                for (int t = 0; t < 2; ++t) {
                    const int k = d + (t << 4);
                    const float4* wr = reinterpret_cast<const float4*>(&Wl[k * WL_STRIDE + (j << 4)]);
                    const float4 w0 = wr[0], w1 = wr[1], w2 = wr[2], w3 = wr[3];
                    float wa = w0.x * o0.x + w0.y * o0.y + w0.z * o0.z + w0.w * o0.w;
                    float wb = w1.x * o1.x + w1.y * o1.y + w1.z * o1.z + w1.w * o1.w;
                    wa += w2.x * o2.x + w2.y * o2.y + w2.z * o2.z + w2.w * o2.w;
                    wb += w3.x * o3.x + w3.y * o3.y + w3.z * o3.z + w3.w * o3.w;
                    wtb[j * WT_STRIDE + k] = f2bf(wa + wb);
                }
            }
        }
        __syncthreads();
        if (r == 2) break;

        // ===== PB + PA fused (wave-private cw: no internal barrier) =====
        {
            __builtin_amdgcn_s_setprio(1);
            const short8 wf = *reinterpret_cast<const short8*>(&wtb[l15 * WT_STRIDE + (lg4 << 3)]);
            #pragma unroll
            for (int T = 0; T < 4; ++T)
                blogA[T] = __builtin_amdgcn_mfma_f32_16x16x32_bf16(wf, xA[T], blogA[T], 0, 0, 0);
            const int jb = lg4 << 2;
            #pragma unroll
            for (int T = 0; T < 4; ++T) {
                const f32x4 bv = blogA[T];
                const float e0 = (jb + 0 < NJ) ? __expf(bv[0]) : 0.f;
                const float e1 = (jb + 1 < NJ) ? __expf(bv[1]) : 0.f;
                const float e2 = (jb + 2 < NJ) ? __expf(bv[2]) : 0.f;
                const float e3 = (jb + 3 < NJ) ? __expf(bv[3]) : 0.f;
                float ssum = e0 + e1 + e2 + e3;
                ssum += __shfl_xor(ssum, 16);
                ssum += __shfl_xor(ssum, 32);
                const float inv = 1.f / ssum;
                const int il = (T << 4) + l15;          // wave-local column
                cw[w][jb + 0][il] = f2bf(e0 * inv);
                cw[w][jb + 1][il] = f2bf(e1 * inv);
                cw[w][jb + 2][il] = f2bf(e2 * inv);
                cw[w][jb + 3][il] = f2bf(e3 * inv);
            }
            // PA over wave's own 64 i's (2 K-steps), same-wave LDS
            f32x4 yf0 = (f32x4){0.f, 0.f, 0.f, 0.f};
            f32x4 yf1 = (f32x4){0.f, 0.f, 0.f, 0.f};
            #pragma unroll
            for (int ss = 0; ss < 2; ++ss) {
                const short8 ca = *reinterpret_cast<const short8*>(
                    &cw[w][l15][(ss << 5) + (lg4 << 3)]);
                yf0 = __builtin_amdgcn_mfma_f32_16x16x32_bf16(ca, xB[ss][0], yf0, 0, 0, 0);
                yf1 = __builtin_amdgcn_mfma_f32_16x16x32_bf16(ca, xB[ss][1], yf1, 0, 0, 0);
            }
            __builtin_amdgcn_s_setprio(0);
            #pragma unroll
            for (int rr = 0; rr < 4; ++rr) {
                ypart[w][(lg4 << 2) + rr][l15]      = yf0[rr];
                ypart[w][(lg4 << 2) + rr][l15 + 16] = yf1[rr];
            }
        }
        __syncthreads();

        // ===== reduce 8-wave partials -> yb =====
        {
            const int j = tid >> 5, k = tid & 31;
            float s = 0.f;
            #pragma unroll
            for (int ww = 0; ww < 8; ++ww) s += ypart[ww][j][k];
            yb[j * Y_STRIDE + k] = s;
        }
        __syncthreads();
    }

    // ---- final softmax over j, write out[b][0..9] ----
    if (tid < NJ) {
        float m = -1e30f;
        #pragma unroll
        for (int j = 0; j < NJ; ++j) m = fmaxf(m, lgt[j]);
        float sum = 0.f;
        #pragma unroll
        for (int j = 0; j < NJ; ++j) sum += __expf(lgt[j] - m);
        out[b * NJ + tid] = __expf(lgt[tid] - m) / sum;
    }
}

extern "C" void kernel_launch(void* const* d_in, const int* in_sizes, int n_in,
                              void* d_out, int out_size, void* d_ws, size_t ws_size,
                              hipStream_t stream) {
    (void)in_sizes; (void)n_in; (void)d_ws; (void)ws_size; (void)out_size;
    const float* x = (const float*)d_in[0];
    const float* W = (const float*)d_in[1];
    float* out = (float*)d_out;
    hipLaunchKernelGGL(capsnet_kernel, dim3(512), dim3(NT), 0, stream, x, W, out);
}